// Round 7
// baseline (164.451 us; speedup 1.0000x reference)
//
#include <hip/hip_runtime.h>
#include <cstddef>

#define NN 1024
#define CL 384
#define CP 128
#define NH 8
#define KS 32
#define HK 256
#define CHK 32          // j-chunk size
#define NCHK (NN/CHK)   // 32 chunks

typedef float floatx4 __attribute__((ext_vector_type(4)));

template<int CTRL>
__device__ __forceinline__ float dpp_mov(float v) {
    return __int_as_float(__builtin_amdgcn_update_dpp(
        0, __float_as_int(v), CTRL, 0xF, 0xF, true));
}

__device__ __forceinline__ float4 ntload4(const float* p) {
    floatx4 t = __builtin_nontemporal_load((const floatx4*)p);
    float4 r; r.x = t.x; r.y = t.y; r.z = t.z; r.w = t.w;
    return r;
}

// ---------------- Kernel 1: LayerNorm + value projection ----------------
// value[r][m], m = h*32+c  (row-major, m contiguous)
__global__ __launch_bounds__(256) void k_ln_value(
    const float* __restrict__ local_, const float* __restrict__ ln_scale,
    const float* __restrict__ ln_offset, const float* __restrict__ Wv,
    float* __restrict__ value)
{
    __shared__ float ln_s[4][CL];
    const int tid = threadIdx.x;
    const int w = tid >> 6, lane = tid & 63;
    const int r = blockIdx.x * 4 + w;
    const float* lp = local_ + (size_t)r * CL;
    float x[6]; float s1 = 0.f, s2 = 0.f;
#pragma unroll
    for (int k = 0; k < 6; ++k) { x[k] = lp[lane + 64*k]; s1 += x[k]; s2 += x[k]*x[k]; }
#pragma unroll
    for (int m = 1; m < 64; m <<= 1) { s1 += __shfl_xor(s1, m); s2 += __shfl_xor(s2, m); }
    const float mean = s1 * (1.f/CL);
    const float var  = fmaxf(s2 * (1.f/CL) - mean*mean, 0.f);
    const float rstd = rsqrtf(var + 1e-5f);
#pragma unroll
    for (int k = 0; k < 6; ++k) {
        const int c = lane + 64*k;
        ln_s[w][c] = (x[k]-mean)*rstd*ln_scale[c] + ln_offset[c];
    }
    __syncthreads();
    const int m_ = tid;
    float acc0=0.f, acc1=0.f, acc2=0.f, acc3=0.f;
    for (int c0 = 0; c0 < CL; c0 += 8) {
        float wv[8];
#pragma unroll
        for (int cc = 0; cc < 8; ++cc) wv[cc] = Wv[(size_t)(c0+cc)*HK + m_];
        {
            const float4 a = *(const float4*)&ln_s[0][c0];
            const float4 b = *(const float4*)&ln_s[0][c0+4];
            acc0 += a.x*wv[0]+a.y*wv[1]+a.z*wv[2]+a.w*wv[3]+b.x*wv[4]+b.y*wv[5]+b.z*wv[6]+b.w*wv[7];
        }
        {
            const float4 a = *(const float4*)&ln_s[1][c0];
            const float4 b = *(const float4*)&ln_s[1][c0+4];
            acc1 += a.x*wv[0]+a.y*wv[1]+a.z*wv[2]+a.w*wv[3]+b.x*wv[4]+b.y*wv[5]+b.z*wv[6]+b.w*wv[7];
        }
        {
            const float4 a = *(const float4*)&ln_s[2][c0];
            const float4 b = *(const float4*)&ln_s[2][c0+4];
            acc2 += a.x*wv[0]+a.y*wv[1]+a.z*wv[2]+a.w*wv[3]+b.x*wv[4]+b.y*wv[5]+b.z*wv[6]+b.w*wv[7];
        }
        {
            const float4 a = *(const float4*)&ln_s[3][c0];
            const float4 b = *(const float4*)&ln_s[3][c0+4];
            acc3 += a.x*wv[0]+a.y*wv[1]+a.z*wv[2]+a.w*wv[3]+b.x*wv[4]+b.y*wv[5]+b.z*wv[6]+b.w*wv[7];
        }
    }
    const int rb = blockIdx.x*4;
    value[(size_t)(rb+0)*HK + m_] = acc0;
    value[(size_t)(rb+1)*HK + m_] = acc1;
    value[(size_t)(rb+2)*HK + m_] = acc2;
    value[(size_t)(rb+3)*HK + m_] = acc3;
}

// ---------------- Kernel 2: fused pair-bias attention, 1 row / 256-thr block -
// Depth-2 pipeline, chunk=32. Per half-iteration:
//   logits(k) [consume d_k] ; PV(k-1) [value loads; drains only d_{k+1}] ;
//   sched_barrier ; prefetch d_{k+2} (youngest -> survives the raw barrier) ;
//   lgkmcnt(0) ; s_barrier.
__global__ __launch_bounds__(256, 4) void k_attn(
    const float* __restrict__ pair, const int* __restrict__ mask,
    const float* __restrict__ Wa, const float* __restrict__ value,
    const float* __restrict__ Wo, float* __restrict__ outp)
{
    __shared__ float zf[NN];            // mask factor per j
    __shared__ float ps[2][NH][CHK+4];  // p~ chunk, double-buffered, padded
    __shared__ float sep[8*NH];         // [g][h] partial denominators
    __shared__ float ov4[4][64][4];     // PV partials across j-subgroups
    __shared__ float ov[HK];            // normalized attention vector

    const int tid = threadIdx.x;
    const int g = tid >> 5;             // 32-lane group 0..7 (logits role)
    const int sub5 = tid & 31;
    const int i = blockIdx.x;
    const bool bmi = mask[i] != 0;

    for (int k = tid; k < NN; k += 256)
        zf[k] = (bmi && (mask[k] != 0)) ? 1.f : 0.f;

    // W_attn rows sub5*4 .. +3, all 8 heads; wreg[cc*8+h]
    float wreg[32];
    {
        const float4* wp = (const float4*)(Wa + sub5*4*NH);
#pragma unroll
        for (int k = 0; k < 8; ++k) {
            const float4 t4 = wp[k];
            wreg[4*k+0]=t4.x; wreg[4*k+1]=t4.y; wreg[4*k+2]=t4.z; wreg[4*k+3]=t4.w;
        }
    }

    // logits reduce output mapping (levels xor1,xor2,xor8 select; xor4,xor16 sum)
    const int  myh   = (sub5 & 1)*4 + ((sub5 >> 1) & 1)*2 + ((sub5 >> 3) & 1);
    const bool owner = (sub5 & 0x14) == 0;   // 1 writer per (g,h)

    // PV role: wave q handles j = jc + 4k + q ; lane mq owns m-quad
    const int q  = tid >> 6;
    const int mq = tid & 63;
    const int pvh = mq >> 3;
    float4 ac4; ac4.x = ac4.y = ac4.z = ac4.w = 0.f;
    float se_loc = 0.f;

    const float* pb = pair + (size_t)i*NN*CP + sub5*4;

    float4 dA[4], dB[4];

    auto PREFETCH = [&](float4* d, int jc) {
#pragma unroll
        for (int s = 0; s < 4; ++s)
            d[s] = ntload4(pb + (size_t)(jc + g*4 + s)*CP);
    };

    auto LOGITS = [&](const float4* d, int jc, int pbuf) {
#pragma unroll
        for (int s = 0; s < 4; ++s) {
            const float4 cur = d[s];
            float acc[8];
#pragma unroll
            for (int h = 0; h < 8; ++h)
                acc[h] = cur.x*wreg[h] + cur.y*wreg[8+h] + cur.z*wreg[16+h] + cur.w*wreg[24+h];
            const bool b0 = (sub5 & 1) != 0;
            const bool b1 = (sub5 & 2) != 0;
            const bool b3 = (sub5 & 8) != 0;
            float r4[4];
#pragma unroll
            for (int k = 0; k < 4; ++k)
                r4[k] = (b0 ? acc[k+4] : acc[k]) + dpp_mov<0xB1>(b0 ? acc[k] : acc[k+4]); // xor1
            float r2[2];
#pragma unroll
            for (int k = 0; k < 2; ++k)
                r2[k] = (b1 ? r4[k+2] : r4[k]) + dpp_mov<0x4E>(b1 ? r4[k] : r4[k+2]);     // xor2
            float r1 = (b3 ? r2[1] : r2[0]) + dpp_mov<0x128>(b3 ? r2[0] : r2[1]);         // xor8
            r1 += __shfl_xor(r1, 4);
            r1 += __shfl_xor(r1, 16);
            const int jj = g*4 + s;
            const float pt = zf[jc + jj] * __expf(r1);
            se_loc += pt;                        // 4 identical copies per (g,h)
            ps[pbuf][myh][jj] = pt;              // 4 same-addr writers, same value
        }
    };

    auto PV = [&](int jc, int pbuf) {
        const float* vb = value + (size_t)jc*HK + mq*4;
#pragma unroll
        for (int k = 0; k < 8; ++k) {
            const int jj = 4*k + q;
            const float p = ps[pbuf][pvh][jj];
            const float4 v4 = *(const float4*)(vb + (size_t)jj*HK);
            ac4.x += p*v4.x; ac4.y += p*v4.y; ac4.z += p*v4.z; ac4.w += p*v4.w;
        }
    };

    PREFETCH(dA, 0);
    PREFETCH(dB, CHK);
    __syncthreads();        // zf ready (drains initial prefetch once; prologue only)

    for (int it = 0; it < NCHK/2; ++it) {
        const int k0 = it*2;
        // ---- even half: chunk k0 (buffer A / ps[0]) ----
        LOGITS(dA, k0*CHK, 0);
        if (k0 > 0) PV((k0-1)*CHK, 1);
        __builtin_amdgcn_sched_barrier(0);
        if (k0+2 < NCHK) PREFETCH(dA, (k0+2)*CHK);
        asm volatile("s_waitcnt lgkmcnt(0)" ::: "memory");
        __builtin_amdgcn_s_barrier();
        // ---- odd half: chunk k0+1 (buffer B / ps[1]) ----
        LOGITS(dB, (k0+1)*CHK, 1);
        PV(k0*CHK, 0);
        __builtin_amdgcn_sched_barrier(0);
        if (k0+3 < NCHK) PREFETCH(dB, (k0+3)*CHK);
        asm volatile("s_waitcnt lgkmcnt(0)" ::: "memory");
        __builtin_amdgcn_s_barrier();
    }
    // epilogue: PV of the last chunk
    PV((NCHK-1)*CHK, 1);

    if (owner) sep[g*NH + myh] = se_loc;
    ov4[q][mq][0] = ac4.x; ov4[q][mq][1] = ac4.y;
    ov4[q][mq][2] = ac4.z; ov4[q][mq][3] = ac4.w;
    __syncthreads();

    {   // combine j-subgroups, normalize
        const int m = tid;               // 0..255
        const float s4 = ov4[0][m>>2][m&3] + ov4[1][m>>2][m&3]
                       + ov4[2][m>>2][m&3] + ov4[3][m>>2][m&3];
        const int h = m >> 5;
        float se = 0.f;
#pragma unroll
        for (int k = 0; k < 8; ++k) se += sep[k*NH + h];
        const float inv = (se > 0.f) ? (1.f/se) : 0.f;
        ov[m] = s4 * inv;
    }
    __syncthreads();

    // ---- final projection out = ov @ W_out ----
    for (int o = tid; o < CL; o += 256) {
        float a0 = 0.f;
        for (int m = 0; m < HK; m += 4) {
            const float4 x0 = *(const float4*)&ov[m];
            a0 += x0.x*Wo[(size_t)(m+0)*CL + o] + x0.y*Wo[(size_t)(m+1)*CL + o]
                + x0.z*Wo[(size_t)(m+2)*CL + o] + x0.w*Wo[(size_t)(m+3)*CL + o];
        }
        outp[(size_t)i*CL + o] = a0;
    }
}

extern "C" void kernel_launch(void* const* d_in, const int* in_sizes, int n_in,
                              void* d_out, int out_size, void* d_ws, size_t ws_size,
                              hipStream_t stream)
{
    (void)in_sizes; (void)n_in; (void)out_size; (void)ws_size;
    const float* local_ = (const float*)d_in[0];
    const float* pair   = (const float*)d_in[1];
    const int*   mask   = (const int*)d_in[2];
    const float* scale  = (const float*)d_in[3];
    const float* offset = (const float*)d_in[4];
    const float* Wv     = (const float*)d_in[5];
    const float* Wa     = (const float*)d_in[6];
    const float* Wo     = (const float*)d_in[7];
    float* value = (float*)d_ws;          // 1 MiB scratch: [1024][256]
    k_ln_value<<<NN/4, 256, 0, stream>>>(local_, scale, offset, Wv, value);
    k_attn<<<NN, 256, 0, stream>>>(pair, mask, Wa, value, Wo, (float*)d_out);
}

// Round 8
// 154.909 us; speedup vs baseline: 1.0616x; 1.0616x over previous
//
#include <hip/hip_runtime.h>
#include <cstddef>

#define NN 1024
#define CL 384
#define CP 128
#define NH 8
#define KS 32
#define HK 256

typedef float floatx4 __attribute__((ext_vector_type(4)));

template<int CTRL>
__device__ __forceinline__ float dpp_mov(float v) {
    return __int_as_float(__builtin_amdgcn_update_dpp(
        0, __float_as_int(v), CTRL, 0xF, 0xF, true));
}

__device__ __forceinline__ float4 ntload4(const float* p) {
    floatx4 t = __builtin_nontemporal_load((const floatx4*)p);
    float4 r; r.x = t.x; r.y = t.y; r.z = t.z; r.w = t.w;
    return r;
}

// ---------------- Kernel 1: LayerNorm + value projection ----------------
// value[r][m], m = h*32+c  (row-major, m contiguous)
__global__ __launch_bounds__(256) void k_ln_value(
    const float* __restrict__ local_, const float* __restrict__ ln_scale,
    const float* __restrict__ ln_offset, const float* __restrict__ Wv,
    float* __restrict__ value)
{
    __shared__ float ln_s[4][CL];
    const int tid = threadIdx.x;
    const int w = tid >> 6, lane = tid & 63;
    const int r = blockIdx.x * 4 + w;
    const float* lp = local_ + (size_t)r * CL;
    float x[6]; float s1 = 0.f, s2 = 0.f;
#pragma unroll
    for (int k = 0; k < 6; ++k) { x[k] = lp[lane + 64*k]; s1 += x[k]; s2 += x[k]*x[k]; }
#pragma unroll
    for (int m = 1; m < 64; m <<= 1) { s1 += __shfl_xor(s1, m); s2 += __shfl_xor(s2, m); }
    const float mean = s1 * (1.f/CL);
    const float var  = fmaxf(s2 * (1.f/CL) - mean*mean, 0.f);
    const float rstd = rsqrtf(var + 1e-5f);
#pragma unroll
    for (int k = 0; k < 6; ++k) {
        const int c = lane + 64*k;
        ln_s[w][c] = (x[k]-mean)*rstd*ln_scale[c] + ln_offset[c];
    }
    __syncthreads();
    const int m_ = tid;
    float acc0=0.f, acc1=0.f, acc2=0.f, acc3=0.f;
    for (int c0 = 0; c0 < CL; c0 += 8) {
        float wv[8];
#pragma unroll
        for (int cc = 0; cc < 8; ++cc) wv[cc] = Wv[(size_t)(c0+cc)*HK + m_];
        {
            const float4 a = *(const float4*)&ln_s[0][c0];
            const float4 b = *(const float4*)&ln_s[0][c0+4];
            acc0 += a.x*wv[0]+a.y*wv[1]+a.z*wv[2]+a.w*wv[3]+b.x*wv[4]+b.y*wv[5]+b.z*wv[6]+b.w*wv[7];
        }
        {
            const float4 a = *(const float4*)&ln_s[1][c0];
            const float4 b = *(const float4*)&ln_s[1][c0+4];
            acc1 += a.x*wv[0]+a.y*wv[1]+a.z*wv[2]+a.w*wv[3]+b.x*wv[4]+b.y*wv[5]+b.z*wv[6]+b.w*wv[7];
        }
        {
            const float4 a = *(const float4*)&ln_s[2][c0];
            const float4 b = *(const float4*)&ln_s[2][c0+4];
            acc2 += a.x*wv[0]+a.y*wv[1]+a.z*wv[2]+a.w*wv[3]+b.x*wv[4]+b.y*wv[5]+b.z*wv[6]+b.w*wv[7];
        }
        {
            const float4 a = *(const float4*)&ln_s[3][c0];
            const float4 b = *(const float4*)&ln_s[3][c0+4];
            acc3 += a.x*wv[0]+a.y*wv[1]+a.z*wv[2]+a.w*wv[3]+b.x*wv[4]+b.y*wv[5]+b.z*wv[6]+b.w*wv[7];
        }
    }
    const int rb = blockIdx.x*4;
    value[(size_t)(rb+0)*HK + m_] = acc0;
    value[(size_t)(rb+1)*HK + m_] = acc1;
    value[(size_t)(rb+2)*HK + m_] = acc2;
    value[(size_t)(rb+3)*HK + m_] = acc3;
}

// ---------------- Kernel 2: fused attention, wave-local, NO loop barriers ----
// 4 waves/block; wave w owns j in [w*256, (w+1)*256). Per 2-row group:
// lower 32 lanes hold row j_even channels, upper 32 row j_odd.
// DPP/swizzle reduce -> lane holds head myh sum; exp; __shfl broadcast from
// canonical owner lane -> every lane gets p for its PV head; PV inline.
// Cross-wave combine only in the epilogue (one barrier total).
__global__ __launch_bounds__(256, 4) void k_attn(
    const float* __restrict__ pair, const int* __restrict__ mask,
    const float* __restrict__ Wa, const float* __restrict__ value,
    const float* __restrict__ Wo, float* __restrict__ outp)
{
    __shared__ float zf[NN];            // mask factor per j
    __shared__ float sep[4][NH];        // per-wave denominators
    __shared__ float ov4[4][64][4];     // per-wave PV partials
    __shared__ float ov[HK];            // normalized attention vector

    const int tid  = threadIdx.x;
    const int w    = tid >> 6;          // wave 0..3
    const int lane = tid & 63;
    const int sub5 = lane & 31;
    const int half = lane >> 5;         // row parity within group
    const int i = blockIdx.x;
    const bool bmi = mask[i] != 0;

    for (int k = tid; k < NN; k += 256)
        zf[k] = (bmi && (mask[k] != 0)) ? 1.f : 0.f;

    // W_attn rows sub5*4 .. +3, all 8 heads; wreg[cc*8+h]
    float wreg[32];
    {
        const float4* wp = (const float4*)(Wa + sub5*4*NH);
#pragma unroll
        for (int k = 0; k < 8; ++k) {
            const float4 t4 = wp[k];
            wreg[4*k+0]=t4.x; wreg[4*k+1]=t4.y; wreg[4*k+2]=t4.z; wreg[4*k+3]=t4.w;
        }
    }

    // PV head of this lane (owns m = lane*4..+3) and broadcast source lanes
    const int hpv  = lane >> 3;
    const int srcE = ((hpv>>2)&1) + 2*((hpv>>1)&1) + 8*(hpv&1);  // canonical owner, lower half
    const int srcO = srcE + 32;

    const int jbase = w * 256;
    const float* pb = pair + (size_t)i*NN*CP + sub5*4;

    float4 ac4; ac4.x = ac4.y = ac4.z = ac4.w = 0.f;
    float se_loc = 0.f;

    // pair register pipeline: cur = tile t, nxt = tile t+1 (8 rows each)
    float4 cur[4], nxt[4];
#pragma unroll
    for (int s = 0; s < 4; ++s)
        cur[s] = ntload4(pb + (size_t)(jbase + 2*s + half)*CP);

    __syncthreads();        // zf ready (prologue only)

    for (int t = 0; t < 32; ++t) {
        const int j0 = jbase + t*8;
        const int jp = jbase + (((t+1)&31)*8);   // wrap: last prefetch re-reads span start
#pragma unroll
        for (int s = 0; s < 4; ++s)
            nxt[s] = ntload4(pb + (size_t)(jp + 2*s + half)*CP);

#pragma unroll
        for (int s = 0; s < 4; ++s) {
            const float4 c = cur[s];
            float acc[8];
#pragma unroll
            for (int h = 0; h < 8; ++h)
                acc[h] = c.x*wreg[h] + c.y*wreg[8+h] + c.z*wreg[16+h] + c.w*wreg[24+h];
            const bool b0 = (sub5 & 1) != 0;
            const bool b1 = (sub5 & 2) != 0;
            const bool b3 = (sub5 & 8) != 0;
            float r4[4];
#pragma unroll
            for (int k = 0; k < 4; ++k)
                r4[k] = (b0 ? acc[k+4] : acc[k]) + dpp_mov<0xB1>(b0 ? acc[k] : acc[k+4]); // xor1
            float r2[2];
#pragma unroll
            for (int k = 0; k < 2; ++k)
                r2[k] = (b1 ? r4[k+2] : r4[k]) + dpp_mov<0x4E>(b1 ? r4[k] : r4[k+2]);     // xor2
            float r1 = (b3 ? r2[1] : r2[0]) + dpp_mov<0x128>(b3 ? r2[0] : r2[1]);         // xor8
            r1 += __shfl_xor(r1, 4);
            r1 += __shfl_xor(r1, 16);
            const float pe = __expf(r1);          // lane's (half, myh) value
            // broadcast to all lanes for PV head hpv
            const float p_e = __shfl(pe, srcE) * zf[j0 + 2*s];
            const float p_o = __shfl(pe, srcO) * zf[j0 + 2*s + 1];
            se_loc += p_e + p_o;
            const float* vb = value + (size_t)(j0 + 2*s)*HK + lane*4;
            const float4 ve = *(const float4*)vb;
            const float4 vo = *(const float4*)(vb + HK);
            ac4.x += p_e*ve.x + p_o*vo.x;
            ac4.y += p_e*ve.y + p_o*vo.y;
            ac4.z += p_e*ve.z + p_o*vo.z;
            ac4.w += p_e*ve.w + p_o*vo.w;
        }
#pragma unroll
        for (int s = 0; s < 4; ++s) cur[s] = nxt[s];
    }

    // ---- epilogue: combine 4 waves ----
    if ((lane & 7) == 0) sep[w][hpv] = se_loc;    // 8 identical lanes per h; one writes
    ov4[w][lane][0] = ac4.x; ov4[w][lane][1] = ac4.y;
    ov4[w][lane][2] = ac4.z; ov4[w][lane][3] = ac4.w;
    __syncthreads();

    {   // combine, normalize
        const int m = tid;               // 0..255
        const float s4 = ov4[0][m>>2][m&3] + ov4[1][m>>2][m&3]
                       + ov4[2][m>>2][m&3] + ov4[3][m>>2][m&3];
        const int h = m >> 5;
        const float se = sep[0][h] + sep[1][h] + sep[2][h] + sep[3][h];
        const float inv = (se > 0.f) ? (1.f/se) : 0.f;
        ov[m] = s4 * inv;
    }
    __syncthreads();

    // ---- final projection out = ov @ W_out ----
    for (int o = tid; o < CL; o += 256) {
        float a0 = 0.f;
        for (int m = 0; m < HK; m += 4) {
            const float4 x0 = *(const float4*)&ov[m];
            a0 += x0.x*Wo[(size_t)(m+0)*CL + o] + x0.y*Wo[(size_t)(m+1)*CL + o]
                + x0.z*Wo[(size_t)(m+2)*CL + o] + x0.w*Wo[(size_t)(m+3)*CL + o];
        }
        outp[(size_t)i*CL + o] = a0;
    }
}

extern "C" void kernel_launch(void* const* d_in, const int* in_sizes, int n_in,
                              void* d_out, int out_size, void* d_ws, size_t ws_size,
                              hipStream_t stream)
{
    (void)in_sizes; (void)n_in; (void)out_size; (void)ws_size;
    const float* local_ = (const float*)d_in[0];
    const float* pair   = (const float*)d_in[1];
    const int*   mask   = (const int*)d_in[2];
    const float* scale  = (const float*)d_in[3];
    const float* offset = (const float*)d_in[4];
    const float* Wv     = (const float*)d_in[5];
    const float* Wa     = (const float*)d_in[6];
    const float* Wo     = (const float*)d_in[7];
    float* value = (float*)d_ws;          // 1 MiB scratch: [1024][256]
    k_ln_value<<<NN/4, 256, 0, stream>>>(local_, scale, offset, Wv, value);
    k_attn<<<NN, 256, 0, stream>>>(pair, mask, Wa, value, Wo, (float*)d_out);
}